// Round 8
// baseline (3076.117 us; speedup 1.0000x reference)
//
#include <hip/hip_runtime.h>

#define BB 128
#define SS 256
#define WW 20
#define WE 300
#define CE 50
#define CC 100
#define DIN 400
#define KP 416      // DIN padded to 13*32 for MFMA K-loop
#define HID 512
#define Hh 256
#define TT 12
#define START_TAG 9
#define STOP_TAG 10
#define PAD_TAG 11
#define NEGV (-10000.0f)
#define BS 32768   // BB*SS
#define CH 32      // timesteps per chunk
#define NCH 8      // SS/CH
#define CR 4096    // CH*BB rows per direction per chunk

typedef __attribute__((ext_vector_type(8))) short short8;
typedef __attribute__((ext_vector_type(4))) float floatx4;

// byte sizes (all multiples of 256)
#define SZ_EMB_FULL  27262976ull   // 32768*416*2
#define SZ_EMB_CHUNK  6815744ull   // 8192*416*2
#define SZ_WB         1703936ull   // 2048*416*2
#define SZ_BIAS          8192ull   // 2048*4
#define SZ_GATES     33554432ull   // 2048*4096*4
#define SZ_LSTM       8388608ull   // 512*4096*4
#define SZ_FEATS      1572864ull   // 32768*12*4
#define SZ_HBUF        262144ull   // 4*256*128*2 (bf16 h exchange)
#define SZ_CBUF        262144ull   // 2*256*128*4
#define FULL_NEEDED_BYTES (SZ_EMB_FULL + SZ_WB + SZ_BIAS + SZ_GATES + SZ_LSTM + SZ_FEATS + SZ_HBUF + SZ_CBUF)

__device__ __forceinline__ unsigned short f2bf(float x) {
    unsigned int u = __builtin_bit_cast(unsigned int, x);
    unsigned int r = (u + 0x7FFFu + ((u >> 16) & 1u)) >> 16;
    return (unsigned short)r;
}
__device__ __forceinline__ float bf2f(unsigned short u) {
    return __builtin_bit_cast(float, (unsigned int)u << 16);
}

// ---------------- Kernel W: pack W_ih (both dirs) to bf16 [2048][416] + fp32 bias ----------------
__global__ __launch_bounds__(256) void k_w2b(
    const float* __restrict__ wih_f, const float* __restrict__ wih_b,
    const float* __restrict__ bih_f, const float* __restrict__ bhh_f,
    const float* __restrict__ bih_b, const float* __restrict__ bhh_b,
    unsigned short* __restrict__ wB, float* __restrict__ biasC)
{
    int idx = blockIdx.x * 256 + threadIdx.x;
    if (idx < 2048 * KP) {
        int j = idx / KP;
        int col = idx - j * KP;
        const float* src = (j < 1024) ? wih_f : wih_b;
        int jr = j & 1023;
        wB[idx] = (col < DIN) ? f2bf(src[jr * DIN + col]) : 0;
    }
    if (idx < 2048) {
        int jr = idx & 1023;
        biasC[idx] = (idx < 1024) ? (bih_f[jr] + bhh_f[jr]) : (bih_b[jr] + bhh_b[jr]);
    }
}

// ---------------- Kernel A-full: embed entire sequence (bf16 out, K-padded) ----------------
__global__ __launch_bounds__(256) void k_embedF(
    const int* __restrict__ widx, const int* __restrict__ cidx,
    const float* __restrict__ wtab, const float* __restrict__ ctab,
    const float* __restrict__ convw, const float* __restrict__ convb,
    unsigned short* __restrict__ embB)
{
    __shared__ __align__(16) float ce_sh[2][CE][24];
    __shared__ int cid_sh[2][WW];
    __shared__ int wid_sh[2];
    const int tid = threadIdx.x;
    const int pl0 = blockIdx.x * 2;

    int g[2];
    #pragma unroll
    for (int p = 0; p < 2; p++) {
        int pl = pl0 + p;
        int s = pl >> 7, b = pl & 127;
        g[p] = b * SS + s;
    }

    if (tid < 2 * WW) {
        int p = tid / WW, w = tid % WW;
        cid_sh[p][w] = cidx[g[p] * WW + w];
    }
    if (tid < 2) wid_sh[tid] = widx[g[tid]];
    for (int i = tid; i < 2 * CE * 24; i += 256) ((float*)ce_sh)[i] = 0.f;
    __syncthreads();

    for (int i = tid; i < 2 * WW * CE; i += 256) {
        int p = i / (WW * CE);
        int rem = i % (WW * CE);
        int w = rem / CE, ce = rem % CE;
        ce_sh[p][ce][w + 1] = ctab[cid_sh[p][w] * CE + ce];
    }
    for (int i = tid; i < 2 * WE; i += 256) {
        int p = i / WE, col = i % WE;
        embB[(size_t)(pl0 + p) * KP + col] = f2bf(wtab[(size_t)wid_sh[p] * WE + col]);
    }
    for (int i = tid; i < 2 * (KP - DIN); i += 256) {
        int p = i / (KP - DIN), col = DIN + i % (KP - DIN);
        embB[(size_t)(pl0 + p) * KP + col] = 0;
    }
    __syncthreads();

    const int p = tid >> 7;
    const int cc = tid & 127;
    if (cc < CC) {
        float acc[WW];
        #pragma unroll
        for (int w = 0; w < WW; w++) acc[w] = 0.f;
        for (int ce = 0; ce < CE; ce++) {
            float row[24];
            #pragma unroll
            for (int q = 0; q < 6; q++) {
                float4 v = *(const float4*)&ce_sh[p][ce][q * 4];
                row[q * 4 + 0] = v.x; row[q * 4 + 1] = v.y;
                row[q * 4 + 2] = v.z; row[q * 4 + 3] = v.w;
            }
            float c0 = convw[(cc * CE + ce) * 3 + 0];
            float c1 = convw[(cc * CE + ce) * 3 + 1];
            float c2 = convw[(cc * CE + ce) * 3 + 2];
            #pragma unroll
            for (int w = 0; w < WW; w++)
                acc[w] += c0 * row[w] + c1 * row[w + 1] + c2 * row[w + 2];
        }
        float bb = convb[cc];
        float m = 0.f;
        #pragma unroll
        for (int w = 0; w < WW; w++) {
            float v = acc[w] + bb;
            v = v > 0.f ? v : 0.f;
            m = v > m ? v : m;
        }
        embB[(size_t)(pl0 + p) * KP + WE + cc] = f2bf(m);
    }
}

// ---------------- Kernel A-chunk: fallback (embed chunk rows, both dir ranges, bf16) ----------------
__global__ __launch_bounds__(256) void k_embedC(
    const int* __restrict__ widx, const int* __restrict__ cidx,
    const float* __restrict__ wtab, const float* __restrict__ ctab,
    const float* __restrict__ convw, const float* __restrict__ convb,
    unsigned short* __restrict__ embB, int c)
{
    __shared__ __align__(16) float ce_sh[2][CE][24];
    __shared__ int cid_sh[2][WW];
    __shared__ int wid_sh[2];
    const int tid = threadIdx.x;
    const int pl0 = blockIdx.x * 2;

    int part[2], lr[2], g[2];
    #pragma unroll
    for (int p = 0; p < 2; p++) {
        int pl = pl0 + p;
        part[p] = pl >> 12;
        lr[p] = pl & 4095;
        int ls = lr[p] >> 7;
        int b = lr[p] & 127;
        int s = part[p] ? (224 - 32 * c + ls) : (32 * c + ls);
        g[p] = b * SS + s;
    }

    if (tid < 2 * WW) {
        int p = tid / WW, w = tid % WW;
        cid_sh[p][w] = cidx[g[p] * WW + w];
    }
    if (tid < 2) wid_sh[tid] = widx[g[tid]];
    for (int i = tid; i < 2 * CE * 24; i += 256) ((float*)ce_sh)[i] = 0.f;
    __syncthreads();

    for (int i = tid; i < 2 * WW * CE; i += 256) {
        int p = i / (WW * CE);
        int rem = i % (WW * CE);
        int w = rem / CE, ce = rem % CE;
        ce_sh[p][ce][w + 1] = ctab[cid_sh[p][w] * CE + ce];
    }
    for (int i = tid; i < 2 * WE; i += 256) {
        int p = i / WE, col = i % WE;
        embB[(size_t)(part[p] * CR + lr[p]) * KP + col] =
            f2bf(wtab[(size_t)wid_sh[p] * WE + col]);
    }
    for (int i = tid; i < 2 * (KP - DIN); i += 256) {
        int p = i / (KP - DIN), col = DIN + i % (KP - DIN);
        embB[(size_t)(part[p] * CR + lr[p]) * KP + col] = 0;
    }
    __syncthreads();

    const int p = tid >> 7;
    const int cc = tid & 127;
    if (cc < CC) {
        float acc[WW];
        #pragma unroll
        for (int w = 0; w < WW; w++) acc[w] = 0.f;
        for (int ce = 0; ce < CE; ce++) {
            float row[24];
            #pragma unroll
            for (int q = 0; q < 6; q++) {
                float4 v = *(const float4*)&ce_sh[p][ce][q * 4];
                row[q * 4 + 0] = v.x; row[q * 4 + 1] = v.y;
                row[q * 4 + 2] = v.z; row[q * 4 + 3] = v.w;
            }
            float c0 = convw[(cc * CE + ce) * 3 + 0];
            float c1 = convw[(cc * CE + ce) * 3 + 1];
            float c2 = convw[(cc * CE + ce) * 3 + 2];
            #pragma unroll
            for (int w = 0; w < WW; w++)
                acc[w] += c0 * row[w] + c1 * row[w + 1] + c2 * row[w + 2];
        }
        float bb = convb[cc];
        float m = 0.f;
        #pragma unroll
        for (int w = 0; w < WW; w++) {
            float v = acc[w] + bb;
            v = v > 0.f ? v : 0.f;
            m = v > m ? v : m;
        }
        embB[(size_t)(part[p] * CR + lr[p]) * KP + WE + cc] = f2bf(m);
    }
}

// ---------------- Kernel B: bf16 MFMA input projection: gatesC(2048 x 4096) ----------------
__global__ __launch_bounds__(256) void k_projB(
    const unsigned short* __restrict__ ef, const unsigned short* __restrict__ eb,
    const unsigned short* __restrict__ wB, const float* __restrict__ biasC,
    float* __restrict__ gatesC)
{
    __shared__ __align__(16) unsigned short Wt[128 * 40];
    __shared__ __align__(16) unsigned short Et[128 * 40];
    const int tid = threadIdx.x;
    const int rt = blockIdx.x;   // 0..31
    const int jt = blockIdx.y;   // 0..15
    const unsigned short* esrc = (jt >= 8) ? eb : ef;

    const int row = tid >> 1;          // 0..127
    const int half = tid & 1;          // k-half of 32-k tile
    const int lane = tid & 63;
    const int wv = tid >> 6;
    const int wm = wv >> 1, wn = wv & 1;
    const int fr = lane & 15, quad = lane >> 4;

    floatx4 acc[4][4];
    #pragma unroll
    for (int i = 0; i < 4; i++)
        #pragma unroll
        for (int j = 0; j < 4; j++) acc[i][j] = (floatx4){0.f, 0.f, 0.f, 0.f};

    const unsigned short* wrow = wB + (size_t)(jt * 128 + row) * KP + half * 16;
    const unsigned short* erow = esrc + (size_t)(rt * 128 + row) * KP + half * 16;

    for (int kt = 0; kt < 13; kt++) {
        int4 wv0 = *(const int4*)(wrow + kt * 32);
        int4 wv1 = *(const int4*)(wrow + kt * 32 + 8);
        int4 ev0 = *(const int4*)(erow + kt * 32);
        int4 ev1 = *(const int4*)(erow + kt * 32 + 8);
        __syncthreads();
        *(int4*)&Wt[row * 40 + half * 16]     = wv0;
        *(int4*)&Wt[row * 40 + half * 16 + 8] = wv1;
        *(int4*)&Et[row * 40 + half * 16]     = ev0;
        *(int4*)&Et[row * 40 + half * 16 + 8] = ev1;
        __syncthreads();

        short8 af[4], bf[4];
        #pragma unroll
        for (int fi = 0; fi < 4; fi++)
            af[fi] = *(const short8*)&Wt[(wm * 64 + fi * 16 + fr) * 40 + quad * 8];
        #pragma unroll
        for (int fj = 0; fj < 4; fj++)
            bf[fj] = *(const short8*)&Et[(wn * 64 + fj * 16 + fr) * 40 + quad * 8];
        #pragma unroll
        for (int fi = 0; fi < 4; fi++)
            #pragma unroll
            for (int fj = 0; fj < 4; fj++)
                acc[fi][fj] = __builtin_amdgcn_mfma_f32_16x16x32_bf16(
                    af[fi], bf[fj], acc[fi][fj], 0, 0, 0);
    }

    float bias[4][4];
    #pragma unroll
    for (int fi = 0; fi < 4; fi++)
        #pragma unroll
        for (int reg = 0; reg < 4; reg++)
            bias[fi][reg] = biasC[jt * 128 + wm * 64 + fi * 16 + quad * 4 + reg];

    #pragma unroll
    for (int fi = 0; fi < 4; fi++) {
        #pragma unroll
        for (int fj = 0; fj < 4; fj++) {
            int rg = rt * 128 + wn * 64 + fj * 16 + fr;
            int jg = jt * 128 + wm * 64 + fi * 16 + quad * 4;
            #pragma unroll
            for (int reg = 0; reg < 4; reg++)
                gatesC[(size_t)(jg + reg) * CR + rg] = acc[fi][fj][reg] + bias[fi][reg];
        }
    }
}

// ---------------- Kernel C: one LSTM step (k_step2b) ----------------
// grid 512 = dir*256+kg; thr 256 = (kh,b). Weights fp32 wave-uniform -> s_load (K$);
// h exchanged via bf16 buffer [par][dir][kin][b] (coalesced ushort loads, shift-unpack):
// halves the 64 MB/step h-broadcast to 32 MB. lstmC keeps fp32 h for the feats path.
__global__ __launch_bounds__(256) void k_step2b(
    const float* __restrict__ gatesC,
    const float* __restrict__ whh_f, const float* __restrict__ whh_b,
    unsigned short* __restrict__ hstepB, float* __restrict__ cbuf,
    float* __restrict__ lstmC, int t)
{
    __shared__ float psum[4][128];
    const int tid = threadIdx.x;
    const int b = tid & 127;
    const int kh = tid >> 7;
    const int blk = blockIdx.x;
    const int dir = blk >> 8;
    const int kg = blk & 255;
    const int tl = t & (CH - 1);
    const int lr = (dir ? (CH - 1 - tl) : tl) * BB + b;

    float q0 = 0.f, q1 = 0.f, q2 = 0.f, q3 = 0.f, c_old = 0.f;
    const int jb = dir * 1024;
    if (kh == 0) {
        q0 = gatesC[(size_t)(jb + 0 * Hh + kg) * CR + lr];
        q1 = gatesC[(size_t)(jb + 1 * Hh + kg) * CR + lr];
        q2 = gatesC[(size_t)(jb + 2 * Hh + kg) * CR + lr];
        q3 = gatesC[(size_t)(jb + 3 * Hh + kg) * CR + lr];
        if (t > 0) c_old = cbuf[(size_t)(dir * Hh + kg) * BB + b];
    }

    float g0 = 0.f, g1 = 0.f, g2 = 0.f, g3 = 0.f;
    if (t > 0) {
        const float* whh = dir ? whh_b : whh_f;
        const int koff = __builtin_amdgcn_readfirstlane(kh * 128);
        const float* w0 = whh + (size_t)(0 * Hh + kg) * Hh + koff;
        const float* w1 = whh + (size_t)(1 * Hh + kg) * Hh + koff;
        const float* w2 = whh + (size_t)(2 * Hh + kg) * Hh + koff;
        const float* w3 = whh + (size_t)(3 * Hh + kg) * Hh + koff;
        const int par = t & 1;
        const unsigned short* hsrc = hstepB + (size_t)((par * 2 + dir) * Hh + koff) * BB;
        #pragma unroll 4
        for (int kk = 0; kk < 128; kk += 4) {
            float h0 = bf2f(hsrc[(kk + 0) * BB + b]);
            float h1 = bf2f(hsrc[(kk + 1) * BB + b]);
            float h2 = bf2f(hsrc[(kk + 2) * BB + b]);
            float h3 = bf2f(hsrc[(kk + 3) * BB + b]);
            float4 wa = *(const float4*)&w0[kk];
            float4 wb = *(const float4*)&w1[kk];
            float4 wc = *(const float4*)&w2[kk];
            float4 wd = *(const float4*)&w3[kk];
            g0 += h0 * wa.x + h1 * wa.y + h2 * wa.z + h3 * wa.w;
            g1 += h0 * wb.x + h1 * wb.y + h2 * wb.z + h3 * wb.w;
            g2 += h0 * wc.x + h1 * wc.y + h2 * wc.z + h3 * wc.w;
            g3 += h0 * wd.x + h1 * wd.y + h2 * wd.z + h3 * wd.w;
        }
    }

    if (kh) {
        psum[0][b] = g0; psum[1][b] = g1; psum[2][b] = g2; psum[3][b] = g3;
    }
    __syncthreads();
    if (!kh) {
        g0 = (q0 + g0) + psum[0][b];
        g1 = (q1 + g1) + psum[1][b];
        g2 = (q2 + g2) + psum[2][b];
        g3 = (q3 + g3) + psum[3][b];

        float si = 1.f / (1.f + expf(-g0));
        float sf = 1.f / (1.f + expf(-g1));
        float tg = tanhf(g2);
        float so = 1.f / (1.f + expf(-g3));
        float c_new = sf * c_old + si * tg;
        float h_new = so * tanhf(c_new);

        cbuf[(size_t)(dir * Hh + kg) * BB + b] = c_new;
        const int parn = (t + 1) & 1;
        hstepB[(size_t)((parn * 2 + dir) * Hh + kg) * BB + b] = f2bf(h_new);
        lstmC[(size_t)(dir * Hh + kg) * CR + lr] = h_new;
    }
}

// ---------------- Kernel D0: feats = bias ----------------
__global__ __launch_bounds__(256) void k_feats_init(
    const float* __restrict__ h2b, float* __restrict__ feats)
{
    int i = blockIdx.x * 256 + threadIdx.x;
    if (i < BS * TT) feats[i] = h2b[i % TT];
}

// ---------------- Kernel D: accumulate chunk's lstm h into feats ----------------
__global__ __launch_bounds__(256) void k_feats_acc(
    const float* __restrict__ lstmC,
    const float* __restrict__ h2w, float* __restrict__ feats, int c)
{
    __shared__ float ps[TT][128];
    const int part = blockIdx.x >> 5;
    const int ls = blockIdx.x & 31;
    const int b = threadIdx.x & 127;
    const int kh = threadIdx.x >> 7;
    const int s = part ? (224 - 32 * c + ls) : (32 * c + ls);
    const int r = s * BB + b;
    const int k0 = kh * 128;

    float acc[TT];
    #pragma unroll
    for (int t = 0; t < TT; t++) acc[t] = 0.f;
    for (int dk = 0; dk < 128; dk++) {
        float v = lstmC[(size_t)(part * Hh + k0 + dk) * CR + ls * BB + b];
        #pragma unroll
        for (int t = 0; t < TT; t++) acc[t] += v * h2w[t * HID + part * Hh + k0 + dk];
    }
    if (kh) {
        #pragma unroll
        for (int t = 0; t < TT; t++) ps[t][b] = acc[t];
    }
    __syncthreads();
    if (!kh) {
        #pragma unroll
        for (int t = 0; t < TT; t++)
            feats[(size_t)r * TT + t] += acc[t] + ps[t][b];
    }
}

// ---------------- Kernel E: Viterbi forward + backtrace, one wave per batch ----------------
__global__ __launch_bounds__(64) void k_viterbi(
    const float* __restrict__ feats,
    const int* __restrict__ mask, const float* __restrict__ trans,
    float* __restrict__ out)
{
    __shared__ unsigned char bp_sh[SS][TT];
    __shared__ int red[64];
    __shared__ int len_sh;
    const int b = blockIdx.x;
    const int tid = threadIdx.x;
    const int n = tid;

    int partial = 0;
    for (int s = tid; s < SS; s += 64) partial += mask[b * SS + s];
    red[tid] = partial;
    __syncthreads();
    if (tid == 0) {
        int L = 0;
        for (int i = 0; i < 64; i++) L += red[i];
        len_sh = L;
    }
    __syncthreads();
    const int len = len_sh;

    float tr[TT];
    float alpha = NEGV;
    if (n < TT) {
        #pragma unroll
        for (int p = 0; p < TT; p++) tr[p] = trans[p * TT + n];
        alpha = (n == START_TAG) ? 0.f : NEGV;
    }

    for (int s = 0; s < len; s++) {
        float feat = (n < TT) ? feats[(size_t)(s * BB + b) * TT + n] : 0.f;
        float best = -3.0e38f;
        int bpi = 0;
        #pragma unroll
        for (int p = 0; p < TT; p++) {
            float ap = __shfl(alpha, p, 64);
            float sc = (n < TT) ? ((ap + tr[p]) + feat) : -3.0e38f;
            if (sc > best) { best = sc; bpi = p; }
        }
        if (n < TT) {
            bp_sh[s][n] = (unsigned char)bpi;
            alpha = best;
        }
    }

    float term = (n < TT) ? (alpha + trans[STOP_TAG * TT + n]) : -3.0e38f;
    float bs = -3.0e38f;
    int bl = 0;
    #pragma unroll
    for (int p = 0; p < TT; p++) {
        float v = __shfl(term, p, 64);
        if (v > bs) { bs = v; bl = p; }
    }

    if (tid == 0) {
        out[b] = bs;
        int tag = bl;
        for (int s = SS - 1; s >= 0; s--) {
            float o;
            if (s < len) {
                o = (float)tag;
                tag = (int)bp_sh[s][tag];
            } else {
                o = (float)PAD_TAG;
            }
            out[BB + b * SS + s] = o;
        }
    }
}

extern "C" void kernel_launch(void* const* d_in, const int* in_sizes, int n_in,
                              void* d_out, int out_size, void* d_ws, size_t ws_size,
                              hipStream_t stream) {
    const int*   widx  = (const int*)d_in[0];
    const int*   cidx  = (const int*)d_in[1];
    const int*   mask  = (const int*)d_in[2];
    const float* wtab  = (const float*)d_in[3];
    const float* ctab  = (const float*)d_in[4];
    const float* convw = (const float*)d_in[5];
    const float* convb = (const float*)d_in[6];
    const float* wih_f = (const float*)d_in[7];
    const float* whh_f = (const float*)d_in[8];
    const float* bih_f = (const float*)d_in[9];
    const float* bhh_f = (const float*)d_in[10];
    const float* wih_b = (const float*)d_in[11];
    const float* whh_b = (const float*)d_in[12];
    const float* bih_b = (const float*)d_in[13];
    const float* bhh_b = (const float*)d_in[14];
    const float* h2w   = (const float*)d_in[15];
    const float* h2b   = (const float*)d_in[16];
    const float* trans = (const float*)d_in[17];

    const bool full = ws_size >= FULL_NEEDED_BYTES;  // constant per session
    char* base = (char*)d_ws;
    const size_t emb_sz = full ? SZ_EMB_FULL : SZ_EMB_CHUNK;
    unsigned short* embB = (unsigned short*)base;
    unsigned short* wB   = (unsigned short*)(base + emb_sz);
    float* biasC  = (float*)(base + emb_sz + SZ_WB);
    float* gatesC = (float*)(base + emb_sz + SZ_WB + SZ_BIAS);
    float* lstmC  = (float*)(base + emb_sz + SZ_WB + SZ_BIAS + SZ_GATES);
    float* feats  = (float*)(base + emb_sz + SZ_WB + SZ_BIAS + SZ_GATES + SZ_LSTM);
    unsigned short* hstepB = (unsigned short*)(base + emb_sz + SZ_WB + SZ_BIAS + SZ_GATES + SZ_LSTM + SZ_FEATS);
    float* cbuf   = (float*)(base + emb_sz + SZ_WB + SZ_BIAS + SZ_GATES + SZ_LSTM + SZ_FEATS + SZ_HBUF);

    hipLaunchKernelGGL(k_feats_init, dim3((BS * TT + 255) / 256), dim3(256), 0, stream,
                       h2b, feats);
    hipLaunchKernelGGL(k_w2b, dim3((2048 * KP + 255) / 256), dim3(256), 0, stream,
                       wih_f, wih_b, bih_f, bhh_f, bih_b, bhh_b, wB, biasC);
    if (full) {
        hipLaunchKernelGGL(k_embedF, dim3(BS / 2), dim3(256), 0, stream,
                           widx, cidx, wtab, ctab, convw, convb, embB);
    }
    for (int c = 0; c < NCH; c++) {
        if (!full) {
            hipLaunchKernelGGL(k_embedC, dim3(CR), dim3(256), 0, stream,
                               widx, cidx, wtab, ctab, convw, convb, embB, c);
        }
        const unsigned short* ef = full ? (embB + (size_t)(32 * c * BB) * KP) : embB;
        const unsigned short* eb = full ? (embB + (size_t)((224 - 32 * c) * BB) * KP)
                                        : (embB + (size_t)CR * KP);
        hipLaunchKernelGGL(k_projB, dim3(32, 16), dim3(256), 0, stream,
                           ef, eb, wB, biasC, gatesC);
        for (int tl = 0; tl < CH; tl++) {
            hipLaunchKernelGGL(k_step2b, dim3(512), dim3(256), 0, stream,
                               gatesC, whh_f, whh_b, hstepB, cbuf, lstmC, c * CH + tl);
        }
        hipLaunchKernelGGL(k_feats_acc, dim3(64), dim3(256), 0, stream,
                           lstmC, h2w, feats, c);
    }
    hipLaunchKernelGGL(k_viterbi, dim3(BB), dim3(64), 0, stream, feats, mask, trans, (float*)d_out);
}

// Round 9
// 2974.638 us; speedup vs baseline: 1.0341x; 1.0341x over previous
//
#include <hip/hip_runtime.h>

#define BB 128
#define SS 256
#define WW 20
#define WE 300
#define CE 50
#define CC 100
#define DIN 400
#define KP 416      // DIN padded to 13*32 for MFMA K-loop
#define HID 512
#define Hh 256
#define TT 12
#define START_TAG 9
#define STOP_TAG 10
#define PAD_TAG 11
#define NEGV (-10000.0f)
#define BS 32768   // BB*SS
#define CH 32      // timesteps per chunk
#define NCH 8      // SS/CH
#define CR 4096    // CH*BB rows per direction per chunk

typedef __attribute__((ext_vector_type(8))) short short8;
typedef __attribute__((ext_vector_type(4))) float floatx4;

// byte sizes (all multiples of 256)
#define SZ_EMB_FULL  27262976ull   // 32768*416*2
#define SZ_EMB_CHUNK  6815744ull   // 8192*416*2
#define SZ_WB         1703936ull   // 2048*416*2
#define SZ_BIAS          8192ull   // 2048*4
#define SZ_GATES     33554432ull   // 2048*4096*4
#define SZ_LSTM       8388608ull   // 512*4096*4
#define SZ_FEATS      1572864ull   // 32768*12*4
#define SZ_HBUF        524288ull   // 4*256*128*4 (fp32 h exchange — r8's bf16 regressed)
#define SZ_CBUF        262144ull   // 2*256*128*4
#define FULL_NEEDED_BYTES (SZ_EMB_FULL + SZ_WB + SZ_BIAS + SZ_GATES + SZ_LSTM + SZ_FEATS + SZ_HBUF + SZ_CBUF)

__device__ __forceinline__ unsigned short f2bf(float x) {
    unsigned int u = __builtin_bit_cast(unsigned int, x);
    unsigned int r = (u + 0x7FFFu + ((u >> 16) & 1u)) >> 16;
    return (unsigned short)r;
}

// ---------------- Kernel W: pack W_ih (both dirs) to bf16 [2048][416] + fp32 bias ----------------
__global__ __launch_bounds__(256) void k_w2b(
    const float* __restrict__ wih_f, const float* __restrict__ wih_b,
    const float* __restrict__ bih_f, const float* __restrict__ bhh_f,
    const float* __restrict__ bih_b, const float* __restrict__ bhh_b,
    unsigned short* __restrict__ wB, float* __restrict__ biasC)
{
    int idx = blockIdx.x * 256 + threadIdx.x;
    if (idx < 2048 * KP) {
        int j = idx / KP;
        int col = idx - j * KP;
        const float* src = (j < 1024) ? wih_f : wih_b;
        int jr = j & 1023;
        wB[idx] = (col < DIN) ? f2bf(src[jr * DIN + col]) : 0;
    }
    if (idx < 2048) {
        int jr = idx & 1023;
        biasC[idx] = (idx < 1024) ? (bih_f[jr] + bhh_f[jr]) : (bih_b[jr] + bhh_b[jr]);
    }
}

// ---------------- Kernel A-full: embed entire sequence (bf16 out, K-padded) ----------------
__global__ __launch_bounds__(256) void k_embedF(
    const int* __restrict__ widx, const int* __restrict__ cidx,
    const float* __restrict__ wtab, const float* __restrict__ ctab,
    const float* __restrict__ convw, const float* __restrict__ convb,
    unsigned short* __restrict__ embB)
{
    __shared__ __align__(16) float ce_sh[2][CE][24];
    __shared__ int cid_sh[2][WW];
    __shared__ int wid_sh[2];
    const int tid = threadIdx.x;
    const int pl0 = blockIdx.x * 2;

    int g[2];
    #pragma unroll
    for (int p = 0; p < 2; p++) {
        int pl = pl0 + p;
        int s = pl >> 7, b = pl & 127;
        g[p] = b * SS + s;
    }

    if (tid < 2 * WW) {
        int p = tid / WW, w = tid % WW;
        cid_sh[p][w] = cidx[g[p] * WW + w];
    }
    if (tid < 2) wid_sh[tid] = widx[g[tid]];
    for (int i = tid; i < 2 * CE * 24; i += 256) ((float*)ce_sh)[i] = 0.f;
    __syncthreads();

    for (int i = tid; i < 2 * WW * CE; i += 256) {
        int p = i / (WW * CE);
        int rem = i % (WW * CE);
        int w = rem / CE, ce = rem % CE;
        ce_sh[p][ce][w + 1] = ctab[cid_sh[p][w] * CE + ce];
    }
    for (int i = tid; i < 2 * WE; i += 256) {
        int p = i / WE, col = i % WE;
        embB[(size_t)(pl0 + p) * KP + col] = f2bf(wtab[(size_t)wid_sh[p] * WE + col]);
    }
    for (int i = tid; i < 2 * (KP - DIN); i += 256) {
        int p = i / (KP - DIN), col = DIN + i % (KP - DIN);
        embB[(size_t)(pl0 + p) * KP + col] = 0;
    }
    __syncthreads();

    const int p = tid >> 7;
    const int cc = tid & 127;
    if (cc < CC) {
        float acc[WW];
        #pragma unroll
        for (int w = 0; w < WW; w++) acc[w] = 0.f;
        for (int ce = 0; ce < CE; ce++) {
            float row[24];
            #pragma unroll
            for (int q = 0; q < 6; q++) {
                float4 v = *(const float4*)&ce_sh[p][ce][q * 4];
                row[q * 4 + 0] = v.x; row[q * 4 + 1] = v.y;
                row[q * 4 + 2] = v.z; row[q * 4 + 3] = v.w;
            }
            float c0 = convw[(cc * CE + ce) * 3 + 0];
            float c1 = convw[(cc * CE + ce) * 3 + 1];
            float c2 = convw[(cc * CE + ce) * 3 + 2];
            #pragma unroll
            for (int w = 0; w < WW; w++)
                acc[w] += c0 * row[w] + c1 * row[w + 1] + c2 * row[w + 2];
        }
        float bb = convb[cc];
        float m = 0.f;
        #pragma unroll
        for (int w = 0; w < WW; w++) {
            float v = acc[w] + bb;
            v = v > 0.f ? v : 0.f;
            m = v > m ? v : m;
        }
        embB[(size_t)(pl0 + p) * KP + WE + cc] = f2bf(m);
    }
}

// ---------------- Kernel A-chunk: fallback (embed chunk rows, both dir ranges, bf16) ----------------
__global__ __launch_bounds__(256) void k_embedC(
    const int* __restrict__ widx, const int* __restrict__ cidx,
    const float* __restrict__ wtab, const float* __restrict__ ctab,
    const float* __restrict__ convw, const float* __restrict__ convb,
    unsigned short* __restrict__ embB, int c)
{
    __shared__ __align__(16) float ce_sh[2][CE][24];
    __shared__ int cid_sh[2][WW];
    __shared__ int wid_sh[2];
    const int tid = threadIdx.x;
    const int pl0 = blockIdx.x * 2;

    int part[2], lr[2], g[2];
    #pragma unroll
    for (int p = 0; p < 2; p++) {
        int pl = pl0 + p;
        part[p] = pl >> 12;
        lr[p] = pl & 4095;
        int ls = lr[p] >> 7;
        int b = lr[p] & 127;
        int s = part[p] ? (224 - 32 * c + ls) : (32 * c + ls);
        g[p] = b * SS + s;
    }

    if (tid < 2 * WW) {
        int p = tid / WW, w = tid % WW;
        cid_sh[p][w] = cidx[g[p] * WW + w];
    }
    if (tid < 2) wid_sh[tid] = widx[g[tid]];
    for (int i = tid; i < 2 * CE * 24; i += 256) ((float*)ce_sh)[i] = 0.f;
    __syncthreads();

    for (int i = tid; i < 2 * WW * CE; i += 256) {
        int p = i / (WW * CE);
        int rem = i % (WW * CE);
        int w = rem / CE, ce = rem % CE;
        ce_sh[p][ce][w + 1] = ctab[cid_sh[p][w] * CE + ce];
    }
    for (int i = tid; i < 2 * WE; i += 256) {
        int p = i / WE, col = i % WE;
        embB[(size_t)(part[p] * CR + lr[p]) * KP + col] =
            f2bf(wtab[(size_t)wid_sh[p] * WE + col]);
    }
    for (int i = tid; i < 2 * (KP - DIN); i += 256) {
        int p = i / (KP - DIN), col = DIN + i % (KP - DIN);
        embB[(size_t)(part[p] * CR + lr[p]) * KP + col] = 0;
    }
    __syncthreads();

    const int p = tid >> 7;
    const int cc = tid & 127;
    if (cc < CC) {
        float acc[WW];
        #pragma unroll
        for (int w = 0; w < WW; w++) acc[w] = 0.f;
        for (int ce = 0; ce < CE; ce++) {
            float row[24];
            #pragma unroll
            for (int q = 0; q < 6; q++) {
                float4 v = *(const float4*)&ce_sh[p][ce][q * 4];
                row[q * 4 + 0] = v.x; row[q * 4 + 1] = v.y;
                row[q * 4 + 2] = v.z; row[q * 4 + 3] = v.w;
            }
            float c0 = convw[(cc * CE + ce) * 3 + 0];
            float c1 = convw[(cc * CE + ce) * 3 + 1];
            float c2 = convw[(cc * CE + ce) * 3 + 2];
            #pragma unroll
            for (int w = 0; w < WW; w++)
                acc[w] += c0 * row[w] + c1 * row[w + 1] + c2 * row[w + 2];
        }
        float bb = convb[cc];
        float m = 0.f;
        #pragma unroll
        for (int w = 0; w < WW; w++) {
            float v = acc[w] + bb;
            v = v > 0.f ? v : 0.f;
            m = v > m ? v : m;
        }
        embB[(size_t)(part[p] * CR + lr[p]) * KP + WE + cc] = f2bf(m);
    }
}

// ---------------- Kernel B: bf16 MFMA input projection: gatesC(2048 x 4096) ----------------
__global__ __launch_bounds__(256) void k_projB(
    const unsigned short* __restrict__ ef, const unsigned short* __restrict__ eb,
    const unsigned short* __restrict__ wB, const float* __restrict__ biasC,
    float* __restrict__ gatesC)
{
    __shared__ __align__(16) unsigned short Wt[128 * 40];
    __shared__ __align__(16) unsigned short Et[128 * 40];
    const int tid = threadIdx.x;
    const int rt = blockIdx.x;   // 0..31
    const int jt = blockIdx.y;   // 0..15
    const unsigned short* esrc = (jt >= 8) ? eb : ef;

    const int row = tid >> 1;          // 0..127
    const int half = tid & 1;          // k-half of 32-k tile
    const int lane = tid & 63;
    const int wv = tid >> 6;
    const int wm = wv >> 1, wn = wv & 1;
    const int fr = lane & 15, quad = lane >> 4;

    floatx4 acc[4][4];
    #pragma unroll
    for (int i = 0; i < 4; i++)
        #pragma unroll
        for (int j = 0; j < 4; j++) acc[i][j] = (floatx4){0.f, 0.f, 0.f, 0.f};

    const unsigned short* wrow = wB + (size_t)(jt * 128 + row) * KP + half * 16;
    const unsigned short* erow = esrc + (size_t)(rt * 128 + row) * KP + half * 16;

    for (int kt = 0; kt < 13; kt++) {
        int4 wv0 = *(const int4*)(wrow + kt * 32);
        int4 wv1 = *(const int4*)(wrow + kt * 32 + 8);
        int4 ev0 = *(const int4*)(erow + kt * 32);
        int4 ev1 = *(const int4*)(erow + kt * 32 + 8);
        __syncthreads();
        *(int4*)&Wt[row * 40 + half * 16]     = wv0;
        *(int4*)&Wt[row * 40 + half * 16 + 8] = wv1;
        *(int4*)&Et[row * 40 + half * 16]     = ev0;
        *(int4*)&Et[row * 40 + half * 16 + 8] = ev1;
        __syncthreads();

        short8 af[4], bf[4];
        #pragma unroll
        for (int fi = 0; fi < 4; fi++)
            af[fi] = *(const short8*)&Wt[(wm * 64 + fi * 16 + fr) * 40 + quad * 8];
        #pragma unroll
        for (int fj = 0; fj < 4; fj++)
            bf[fj] = *(const short8*)&Et[(wn * 64 + fj * 16 + fr) * 40 + quad * 8];
        #pragma unroll
        for (int fi = 0; fi < 4; fi++)
            #pragma unroll
            for (int fj = 0; fj < 4; fj++)
                acc[fi][fj] = __builtin_amdgcn_mfma_f32_16x16x32_bf16(
                    af[fi], bf[fj], acc[fi][fj], 0, 0, 0);
    }

    float bias[4][4];
    #pragma unroll
    for (int fi = 0; fi < 4; fi++)
        #pragma unroll
        for (int reg = 0; reg < 4; reg++)
            bias[fi][reg] = biasC[jt * 128 + wm * 64 + fi * 16 + quad * 4 + reg];

    #pragma unroll
    for (int fi = 0; fi < 4; fi++) {
        #pragma unroll
        for (int fj = 0; fj < 4; fj++) {
            int rg = rt * 128 + wn * 64 + fj * 16 + fr;
            int jg = jt * 128 + wm * 64 + fi * 16 + quad * 4;
            #pragma unroll
            for (int reg = 0; reg < 4; reg++)
                gatesC[(size_t)(jg + reg) * CR + rg] = acc[fi][fj][reg] + bias[fi][reg];
        }
    }
}

// ---------------- Kernel C: one LSTM step (k_step2c) ----------------
// grid 512 = dir(2) x kp(128: kout pair) x bh(2: b half); thr 256, wave = (kh, kout_l)
// (both wave-uniform -> weights stay on the s_load/K$ path). h loads scalar fp32,
// 64-lane coalesced. Identical FMA/summation order to r7's k_step2 (bit-identical
// result); only the sharing geometry changes: block reads 64 KB of h instead of
// 128 KB -> h-broadcast 64 -> 32 MB/step. Clean A/B for L2-BW-bound vs launch-bound.
__global__ __launch_bounds__(256) void k_step2c(
    const float* __restrict__ gatesC,
    const float* __restrict__ whh_f, const float* __restrict__ whh_b,
    float* __restrict__ hbuf, float* __restrict__ cbuf, float* __restrict__ lstmC,
    int t)
{
    __shared__ float psum[4][2][64];   // [gate][kout_l][b_l]
    const int tid = threadIdx.x;
    const int b_l = tid & 63;
    const int kout_l = (tid >> 6) & 1;
    const int kh = tid >> 7;
    const int blk = blockIdx.x;
    const int dir = blk >> 8;
    const int kp = (blk >> 1) & 127;
    const int bh = blk & 1;
    const int kg = kp * 2 + kout_l;
    const int b = bh * 64 + b_l;
    const int tl = t & (CH - 1);
    const int lr = (dir ? (CH - 1 - tl) : tl) * BB + b;

    float q0 = 0.f, q1 = 0.f, q2 = 0.f, q3 = 0.f, c_old = 0.f;
    const int jb = dir * 1024;
    if (kh == 0) {
        q0 = gatesC[(size_t)(jb + 0 * Hh + kg) * CR + lr];
        q1 = gatesC[(size_t)(jb + 1 * Hh + kg) * CR + lr];
        q2 = gatesC[(size_t)(jb + 2 * Hh + kg) * CR + lr];
        q3 = gatesC[(size_t)(jb + 3 * Hh + kg) * CR + lr];
        if (t > 0) c_old = cbuf[(size_t)(dir * Hh + kg) * BB + b];
    }

    float g0 = 0.f, g1 = 0.f, g2 = 0.f, g3 = 0.f;
    if (t > 0) {
        const float* whh = dir ? whh_b : whh_f;
        const int kgs = __builtin_amdgcn_readfirstlane(kg);
        const int koff = __builtin_amdgcn_readfirstlane(kh * 128);
        const float* w0 = whh + (size_t)(0 * Hh + kgs) * Hh + koff;
        const float* w1 = whh + (size_t)(1 * Hh + kgs) * Hh + koff;
        const float* w2 = whh + (size_t)(2 * Hh + kgs) * Hh + koff;
        const float* w3 = whh + (size_t)(3 * Hh + kgs) * Hh + koff;
        const int par = t & 1;
        const float* hsrc = hbuf + (size_t)((par * 2 + dir) * Hh + koff) * BB;
        #pragma unroll 4
        for (int kk = 0; kk < 128; kk += 4) {
            float h0 = hsrc[(kk + 0) * BB + b];
            float h1 = hsrc[(kk + 1) * BB + b];
            float h2 = hsrc[(kk + 2) * BB + b];
            float h3 = hsrc[(kk + 3) * BB + b];
            float4 wa = *(const float4*)&w0[kk];
            float4 wb = *(const float4*)&w1[kk];
            float4 wc = *(const float4*)&w2[kk];
            float4 wd = *(const float4*)&w3[kk];
            g0 += h0 * wa.x + h1 * wa.y + h2 * wa.z + h3 * wa.w;
            g1 += h0 * wb.x + h1 * wb.y + h2 * wb.z + h3 * wb.w;
            g2 += h0 * wc.x + h1 * wc.y + h2 * wc.z + h3 * wc.w;
            g3 += h0 * wd.x + h1 * wd.y + h2 * wd.z + h3 * wd.w;
        }
    }

    if (kh) {
        psum[0][kout_l][b_l] = g0; psum[1][kout_l][b_l] = g1;
        psum[2][kout_l][b_l] = g2; psum[3][kout_l][b_l] = g3;
    }
    __syncthreads();
    if (!kh) {
        g0 = (q0 + g0) + psum[0][kout_l][b_l];
        g1 = (q1 + g1) + psum[1][kout_l][b_l];
        g2 = (q2 + g2) + psum[2][kout_l][b_l];
        g3 = (q3 + g3) + psum[3][kout_l][b_l];

        float si = 1.f / (1.f + expf(-g0));
        float sf = 1.f / (1.f + expf(-g1));
        float tg = tanhf(g2);
        float so = 1.f / (1.f + expf(-g3));
        float c_new = sf * c_old + si * tg;
        float h_new = so * tanhf(c_new);

        cbuf[(size_t)(dir * Hh + kg) * BB + b] = c_new;
        const int parn = (t + 1) & 1;
        hbuf[(size_t)((parn * 2 + dir) * Hh + kg) * BB + b] = h_new;
        lstmC[(size_t)(dir * Hh + kg) * CR + lr] = h_new;
    }
}

// ---------------- Kernel D0: feats = bias ----------------
__global__ __launch_bounds__(256) void k_feats_init(
    const float* __restrict__ h2b, float* __restrict__ feats)
{
    int i = blockIdx.x * 256 + threadIdx.x;
    if (i < BS * TT) feats[i] = h2b[i % TT];
}

// ---------------- Kernel D: accumulate chunk's lstm h into feats ----------------
__global__ __launch_bounds__(256) void k_feats_acc(
    const float* __restrict__ lstmC,
    const float* __restrict__ h2w, float* __restrict__ feats, int c)
{
    __shared__ float ps[TT][128];
    const int part = blockIdx.x >> 5;
    const int ls = blockIdx.x & 31;
    const int b = threadIdx.x & 127;
    const int kh = threadIdx.x >> 7;
    const int s = part ? (224 - 32 * c + ls) : (32 * c + ls);
    const int r = s * BB + b;
    const int k0 = kh * 128;

    float acc[TT];
    #pragma unroll
    for (int t = 0; t < TT; t++) acc[t] = 0.f;
    for (int dk = 0; dk < 128; dk++) {
        float v = lstmC[(size_t)(part * Hh + k0 + dk) * CR + ls * BB + b];
        #pragma unroll
        for (int t = 0; t < TT; t++) acc[t] += v * h2w[t * HID + part * Hh + k0 + dk];
    }
    if (kh) {
        #pragma unroll
        for (int t = 0; t < TT; t++) ps[t][b] = acc[t];
    }
    __syncthreads();
    if (!kh) {
        #pragma unroll
        for (int t = 0; t < TT; t++)
            feats[(size_t)r * TT + t] += acc[t] + ps[t][b];
    }
}

// ---------------- Kernel E: Viterbi forward + backtrace, one wave per batch ----------------
__global__ __launch_bounds__(64) void k_viterbi(
    const float* __restrict__ feats,
    const int* __restrict__ mask, const float* __restrict__ trans,
    float* __restrict__ out)
{
    __shared__ unsigned char bp_sh[SS][TT];
    __shared__ int red[64];
    __shared__ int len_sh;
    const int b = blockIdx.x;
    const int tid = threadIdx.x;
    const int n = tid;

    int partial = 0;
    for (int s = tid; s < SS; s += 64) partial += mask[b * SS + s];
    red[tid] = partial;
    __syncthreads();
    if (tid == 0) {
        int L = 0;
        for (int i = 0; i < 64; i++) L += red[i];
        len_sh = L;
    }
    __syncthreads();
    const int len = len_sh;

    float tr[TT];
    float alpha = NEGV;
    if (n < TT) {
        #pragma unroll
        for (int p = 0; p < TT; p++) tr[p] = trans[p * TT + n];
        alpha = (n == START_TAG) ? 0.f : NEGV;
    }

    for (int s = 0; s < len; s++) {
        float feat = (n < TT) ? feats[(size_t)(s * BB + b) * TT + n] : 0.f;
        float best = -3.0e38f;
        int bpi = 0;
        #pragma unroll
        for (int p = 0; p < TT; p++) {
            float ap = __shfl(alpha, p, 64);
            float sc = (n < TT) ? ((ap + tr[p]) + feat) : -3.0e38f;
            if (sc > best) { best = sc; bpi = p; }
        }
        if (n < TT) {
            bp_sh[s][n] = (unsigned char)bpi;
            alpha = best;
        }
    }

    float term = (n < TT) ? (alpha + trans[STOP_TAG * TT + n]) : -3.0e38f;
    float bs = -3.0e38f;
    int bl = 0;
    #pragma unroll
    for (int p = 0; p < TT; p++) {
        float v = __shfl(term, p, 64);
        if (v > bs) { bs = v; bl = p; }
    }

    if (tid == 0) {
        out[b] = bs;
        int tag = bl;
        for (int s = SS - 1; s >= 0; s--) {
            float o;
            if (s < len) {
                o = (float)tag;
                tag = (int)bp_sh[s][tag];
            } else {
                o = (float)PAD_TAG;
            }
            out[BB + b * SS + s] = o;
        }
    }
}

extern "C" void kernel_launch(void* const* d_in, const int* in_sizes, int n_in,
                              void* d_out, int out_size, void* d_ws, size_t ws_size,
                              hipStream_t stream) {
    const int*   widx  = (const int*)d_in[0];
    const int*   cidx  = (const int*)d_in[1];
    const int*   mask  = (const int*)d_in[2];
    const float* wtab  = (const float*)d_in[3];
    const float* ctab  = (const float*)d_in[4];
    const float* convw = (const float*)d_in[5];
    const float* convb = (const float*)d_in[6];
    const float* wih_f = (const float*)d_in[7];
    const float* whh_f = (const float*)d_in[8];
    const float* bih_f = (const float*)d_in[9];
    const float* bhh_f = (const float*)d_in[10];
    const float* wih_b = (const float*)d_in[11];
    const float* whh_b = (const float*)d_in[12];
    const float* bih_b = (const float*)d_in[13];
    const float* bhh_b = (const float*)d_in[14];
    const float* h2w   = (const float*)d_in[15];
    const float* h2b   = (const float*)d_in[16];
    const float* trans = (const float*)d_in[17];

    const bool full = ws_size >= FULL_NEEDED_BYTES;  // constant per session
    char* base = (char*)d_ws;
    const size_t emb_sz = full ? SZ_EMB_FULL : SZ_EMB_CHUNK;
    unsigned short* embB = (unsigned short*)base;
    unsigned short* wB   = (unsigned short*)(base + emb_sz);
    float* biasC  = (float*)(base + emb_sz + SZ_WB);
    float* gatesC = (float*)(base + emb_sz + SZ_WB + SZ_BIAS);
    float* lstmC  = (float*)(base + emb_sz + SZ_WB + SZ_BIAS + SZ_GATES);
    float* feats  = (float*)(base + emb_sz + SZ_WB + SZ_BIAS + SZ_GATES + SZ_LSTM);
    float* hbuf   = (float*)(base + emb_sz + SZ_WB + SZ_BIAS + SZ_GATES + SZ_LSTM + SZ_FEATS);
    float* cbuf   = (float*)(base + emb_sz + SZ_WB + SZ_BIAS + SZ_GATES + SZ_LSTM + SZ_FEATS + SZ_HBUF);

    hipLaunchKernelGGL(k_feats_init, dim3((BS * TT + 255) / 256), dim3(256), 0, stream,
                       h2b, feats);
    hipLaunchKernelGGL(k_w2b, dim3((2048 * KP + 255) / 256), dim3(256), 0, stream,
                       wih_f, wih_b, bih_f, bhh_f, bih_b, bhh_b, wB, biasC);
    if (full) {
        hipLaunchKernelGGL(k_embedF, dim3(BS / 2), dim3(256), 0, stream,
                           widx, cidx, wtab, ctab, convw, convb, embB);
    }
    for (int c = 0; c < NCH; c++) {
        if (!full) {
            hipLaunchKernelGGL(k_embedC, dim3(CR), dim3(256), 0, stream,
                               widx, cidx, wtab, ctab, convw, convb, embB, c);
        }
        const unsigned short* ef = full ? (embB + (size_t)(32 * c * BB) * KP) : embB;
        const unsigned short* eb = full ? (embB + (size_t)((224 - 32 * c) * BB) * KP)
                                        : (embB + (size_t)CR * KP);
        hipLaunchKernelGGL(k_projB, dim3(32, 16), dim3(256), 0, stream,
                           ef, eb, wB, biasC, gatesC);
        for (int tl = 0; tl < CH; tl++) {
            hipLaunchKernelGGL(k_step2c, dim3(512), dim3(256), 0, stream,
                               gatesC, whh_f, whh_b, hbuf, cbuf, lstmC, c * CH + tl);
        }
        hipLaunchKernelGGL(k_feats_acc, dim3(64), dim3(256), 0, stream,
                           lstmC, h2w, feats, c);
    }
    hipLaunchKernelGGL(k_viterbi, dim3(BB), dim3(64), 0, stream, feats, mask, trans, (float*)d_out);
}